// Round 19
// baseline (180.491 us; speedup 1.0000x reference)
//
#include <hip/hip_runtime.h>

typedef unsigned short u16;
typedef unsigned int u32;
typedef u16 u16x8 __attribute__((ext_vector_type(8)));
typedef u16 u16x4 __attribute__((ext_vector_type(4)));
typedef short bfx8 __attribute__((ext_vector_type(8)));
typedef float f32x4 __attribute__((ext_vector_type(4)));

#define AS1 __attribute__((address_space(1)))
#define AS3 __attribute__((address_space(3)))

__device__ __forceinline__ u16 f2bf(float f) {
  union { float f; u32 u; } c; c.f = f;
  u32 u = c.u;
  u += 0x7fffu + ((u >> 16) & 1u);
  return (u16)(u >> 16);
}

__device__ __forceinline__ float bf2f(u16 b) {
  union { u32 u; float f; } c; c.u = ((u32)b) << 16;
  return c.f;
}

__device__ __forceinline__ u32 cvt_pk_bf16(float lo, float hi) {
  u32 r;
  asm("v_cvt_pk_bf16_f32 %0, %1, %2" : "=v"(r) : "v"(lo), "v"(hi));
  return r;
}

__device__ __forceinline__ float fexp2(float x) {
  float r;
  asm("v_exp_f32 %0, %1" : "=v"(r) : "v"(x));
  return r;
}

// ---------------- LN row helpers (D=512) ----------------
__device__ __forceinline__ void ln_core(float f[8], const float* __restrict__ g,
                                        const float* __restrict__ be,
                                        u16* __restrict__ out, int gw, int lane) {
  float s = 0.f, q = 0.f;
#pragma unroll
  for (int e = 0; e < 8; ++e) { s += f[e]; q += f[e] * f[e]; }
#pragma unroll
  for (int m = 1; m < 64; m <<= 1) { s += __shfl_xor(s, m); q += __shfl_xor(q, m); }
  float mean = s * (1.f / 512.f);
  float var = q * (1.f / 512.f) - mean * mean;
  float rs = rsqrtf(var + 1e-5f);
  const float4* g4 = (const float4*)g;
  const float4* b4 = (const float4*)be;
  float4 ga = g4[2 * lane], gb = g4[2 * lane + 1];
  float4 ba = b4[2 * lane], bb = b4[2 * lane + 1];
  float gv[8] = {ga.x, ga.y, ga.z, ga.w, gb.x, gb.y, gb.z, gb.w};
  float bv[8] = {ba.x, ba.y, ba.z, ba.w, bb.x, bb.y, bb.z, bb.w};
  u16x8 o;
#pragma unroll
  for (int e = 0; e < 8; ++e) o[e] = f2bf((f[e] - mean) * rs * gv[e] + bv[e]);
  ((u16x8*)(out + (size_t)gw * 512))[lane] = o;
}

__device__ __forceinline__ void ln_row_f32(const float* __restrict__ x, const float* __restrict__ g,
                                           const float* __restrict__ be, u16* __restrict__ out,
                                           int gw, int lane) {
  const float4* row = (const float4*)(x + (size_t)gw * 512);
  float4 a = row[2 * lane], b = row[2 * lane + 1];
  float f[8] = {a.x, a.y, a.z, a.w, b.x, b.y, b.z, b.w};
  ln_core(f, g, be, out, gw, lane);
}

// ---------------- merged: 6 weight cvts (gamma-folded where needed) + 2 LNs + LN-commute prep ----------------
// blocks 0..4095: weight cvt; 4096..6143: LN(rna); 6144..7167: LN(protein)
// blocks 7168..7807: column reductions (640 blocks x 4 waves = 2560 waves: 512 qc + 2048 f1)
__global__ __launch_bounds__(256) void cvtln_kernel(const float* __restrict__ a0, const float* __restrict__ a1,
                                                    const float* __restrict__ a2, const float* __restrict__ a3,
                                                    const float* __restrict__ a4, const float* __restrict__ a5,
                                                    u16* __restrict__ b0, u16* __restrict__ b1,
                                                    u16* __restrict__ b2, u16* __restrict__ b3,
                                                    u16* __restrict__ b4, u16* __restrict__ b5,
                                                    const float* __restrict__ x, const float* __restrict__ g,
                                                    const float* __restrict__ be, u16* __restrict__ lnout,
                                                    const float* __restrict__ xp, const float* __restrict__ gp,
                                                    const float* __restrict__ bep, u16* __restrict__ lnoutp,
                                                    const float* __restrict__ g11, const float* __restrict__ be11,
                                                    const float* __restrict__ g2, const float* __restrict__ be2,
                                                    float* __restrict__ s_qc, float* __restrict__ badd_qc,
                                                    float* __restrict__ s_f1, float* __restrict__ badd_f1) {
  if (blockIdx.x < 4096) {
    int i = blockIdx.x * 256 + threadIdx.x;
    const float* s; u16* d; int off; int fold = 0;
    if      (i < 196608) { s = a0; d = b0; off = i; }
    else if (i < 262144) { s = a1; d = b1; off = i - 196608; }
    else if (i < 458752) { s = a2; d = b2; off = i - 262144; fold = (off < 65536) ? 1 : 0; }
    else if (i < 524288) { s = a3; d = b3; off = i - 458752; }
    else if (i < 786432) { s = a4; d = b4; off = i - 524288; fold = 2; }
    else                 { s = a5; d = b5; off = i - 786432; }
    float4 v = ((const float4*)s)[off];
    if (fold) {
      const float* gf = (fold == 1) ? g11 : g2;
      int base = (off * 4) & 511;
      v.x *= gf[base]; v.y *= gf[base + 1]; v.z *= gf[base + 2]; v.w *= gf[base + 3];
    }
    u16x4 o;
    o[0] = f2bf(v.x); o[1] = f2bf(v.y); o[2] = f2bf(v.z); o[3] = f2bf(v.w);
    ((u16x4*)d)[off] = o;
  } else if (blockIdx.x < 6144) {
    int gw = ((blockIdx.x - 4096) * 256 + threadIdx.x) >> 6;
    ln_row_f32(x, g, be, lnout, gw, threadIdx.x & 63);
  } else if (blockIdx.x < 7168) {
    int gw = ((blockIdx.x - 6144) * 256 + threadIdx.x) >> 6;
    ln_row_f32(xp, gp, bep, lnoutp, gw, threadIdx.x & 63);
  } else {
    // column reductions: exactly 2560 valid waves (512 qc + 2048 f1)
    int wv = (blockIdx.x - 7168) * 4 + (threadIdx.x >> 6);
    if (wv >= 2560) return;
    int lane = threadIdx.x & 63;
    const float* W; const float* gm; const float* bt; float* so; float* bo; int c;
    if (wv < 512) { W = a2; gm = g11; bt = be11; so = s_qc; bo = badd_qc; c = wv; }
    else          { W = a4; gm = g2;  bt = be2;  so = s_f1; bo = badd_f1; c = wv - 512; }
    const float* row = W + (size_t)c * 512 + lane * 8;
    float sv = 0.f, bv = 0.f;
#pragma unroll
    for (int e = 0; e < 8; ++e) {
      int k = lane * 8 + e;
      float wvl = row[e];
      sv = fmaf(gm[k], wvl, sv);
      bv = fmaf(bt[k], wvl, bv);
    }
#pragma unroll
    for (int m = 1; m < 64; m <<= 1) { sv += __shfl_xor(sv, m); bv += __shfl_xor(bv, m); }
    if (lane == 0) { so[c] = sv; bo[c] = bv; }
  }
}

// ---------------- V transpose body ----------------
__device__ __forceinline__ void vt_body(const u16* __restrict__ vB, u16* __restrict__ vt,
                                        int stride, int S, int xblk, int b, int h) {
  __shared__ u16 lt[64 * 68];
  const int t = threadIdx.x;
  const int sr = t >> 3, dc = (t & 7) * 8;
#pragma unroll
  for (int p = 0; p < 2; ++p) {
    int s = xblk * 64 + sr + p * 32;
    u16x8 v = *(const u16x8*)(vB + (size_t)(s * 8 + b) * stride + h * 64 + dc);
    u16x4 lo, hi;
    lo[0]=v[0]; lo[1]=v[1]; lo[2]=v[2]; lo[3]=v[3];
    hi[0]=v[4]; hi[1]=v[5]; hi[2]=v[6]; hi[3]=v[7];
    *(u16x4*)&lt[(sr + p * 32) * 68 + dc] = lo;
    *(u16x4*)&lt[(sr + p * 32) * 68 + dc + 4] = hi;
  }
  __syncthreads();
#pragma unroll
  for (int p = 0; p < 2; ++p) {
    int d = sr + p * 32;
    u16x8 o;
#pragma unroll
    for (int e = 0; e < 8; ++e) o[e] = lt[(dc + e) * 68 + d];
    *(u16x8*)(vt + ((size_t)(b * 8 + h) * 64 + d) * S + xblk * 64 + dc) = o;
  }
}

__global__ __launch_bounds__(256) void vt2_kernel(const u16* __restrict__ v0, u16* __restrict__ t0,
                                                  const u16* __restrict__ v1, u16* __restrict__ t1) {
  int id = blockIdx.x;
  if (id < 1024) {
    vt_body(v0, t0, 1536, 1024, id & 15, (id >> 4) & 7, id >> 7);
  } else {
    int l = id - 1024;
    vt_body(v1, t1, 1024, 512, l & 7, (l >> 3) & 7, l >> 6);
  }
}

// ---------------- gemm8 body ----------------
// EPI: 0 bf16 | 1 bf16+relu | 3 fp32res->bf16 | 4 bf16res->bf16 | 5 bf16res->fp32
//      8 bf16 + fused-LN-on-A (raw A, gamma-folded W, commuted epilogue) | 9 = 8 + relu
// EPI 8/9 require K == 512. Stats table aliased onto staging LDS (dead after K-loop).
template <int EPI, int BM, int BN, int WRg>
__device__ __forceinline__ void gemm8_body(const u16* __restrict__ A,
                                           const u16* __restrict__ Bw,
                                           const float* __restrict__ bias,
                                           const void* __restrict__ res,
                                           void* __restrict__ Cout,
                                           int M, int K, int bn, int bm,
                                           u16* __restrict__ lds,
                                           const float* __restrict__ scol = nullptr,
                                           const float* __restrict__ badd = nullptr) {
  constexpr bool LNA = (EPI == 8 || EPI == 9);
  constexpr int WCg = 8 / WRg;
  constexpr int RPW = BM / WRg;
  constexpr int IM = RPW / 16;
  constexpr int CPW = BN / WCg;
  constexpr int JN = CPW / 16;
  constexpr int LD = (BM + BN) / 64;
  u16* lA = lds;
  u16* lB = lds + 2 * BM * 64;
  float2* statsL = (float2*)lds;   // aliased; used only after the K-loop
  const int tid = threadIdx.x;
  const int lane = tid & 63, w = tid >> 6;
  const int wr = w / WCg, wc = w % WCg;
  const int r15 = lane & 15, kg = lane >> 4;
  const int xr = (r15 & 7) << 4;

  f32x4 acc[IM][JN] = {};
  float sA[IM] = {}, sQ[IM] = {};

  const int lrw = tid >> 3;
  const int lcl = ((tid & 7) * 8) ^ ((lrw & 7) * 8);
  const u16* gA = A + (size_t)(bn + lrw) * K + lcl;
  const u16* gB = Bw + (size_t)(bm + lrw) * K + lcl;
  const int ldsbase = (w * 8) * 64;

#define STAGE8(buf, t) do {                                                               \
    _Pragma("unroll")                                                                     \
    for (int i_ = 0; i_ < BM / 64; ++i_)                                                  \
      __builtin_amdgcn_global_load_lds((AS1 u32*)(gA + (size_t)(i_ * 64) * K + (t) * 64), \
                                       (AS3 u32*)&lA[(buf) * BM * 64 + i_ * 4096 + ldsbase], 16, 0, 0);\
    _Pragma("unroll")                                                                     \
    for (int i_ = 0; i_ < BN / 64; ++i_)                                                  \
      __builtin_amdgcn_global_load_lds((AS1 u32*)(gB + (size_t)(i_ * 64) * K + (t) * 64), \
                                       (AS3 u32*)&lB[(buf) * BN * 64 + i_ * 4096 + ldsbase], 16, 0, 0);\
  } while (0)

  const int nk = K >> 6;
  STAGE8(0, 0);
  for (int t = 0; t < nk; ++t) {
    const int cur = t & 1;
    if (t + 1 < nk) {
      STAGE8(cur ^ 1, t + 1);
      if constexpr (LD == 3)      asm volatile("s_waitcnt vmcnt(3)" ::: "memory");
      else if constexpr (LD == 4) asm volatile("s_waitcnt vmcnt(4)" ::: "memory");
      else                        asm volatile("s_waitcnt vmcnt(8)" ::: "memory");
    } else {
      asm volatile("s_waitcnt vmcnt(0)" ::: "memory");
    }
    __builtin_amdgcn_sched_barrier(0);
    __builtin_amdgcn_s_barrier();
    __builtin_amdgcn_sched_barrier(0);

    const char* Ac = (const char*)&lA[cur * BM * 64];
    const char* Bc = (const char*)&lB[cur * BN * 64];
    __builtin_amdgcn_s_setprio(1);
#pragma unroll
    for (int kk = 0; kk < 2; ++kk) {
      bfx8 a[IM], b[JN];
#pragma unroll
      for (int i = 0; i < IM; ++i)
        a[i] = *(const bfx8*)(Ac + (wr * RPW + i * 16 + r15) * 128 + ((kk * 64 + kg * 16) ^ xr));
#pragma unroll
      for (int j = 0; j < JN; ++j)
        b[j] = *(const bfx8*)(Bc + (wc * CPW + j * 16 + r15) * 128 + ((kk * 64 + kg * 16) ^ xr));
      if constexpr (LNA) {
#pragma unroll
        for (int i = 0; i < IM; ++i)
#pragma unroll
          for (int e = 0; e < 8; ++e) {
            float xv = bf2f((u16)a[i][e]);
            sA[i] += xv;
            sQ[i] = fmaf(xv, xv, sQ[i]);
          }
      }
#pragma unroll
      for (int i = 0; i < IM; ++i)
#pragma unroll
        for (int j = 0; j < JN; ++j)
          acc[i][j] = __builtin_amdgcn_mfma_f32_16x16x32_bf16(a[i], b[j], acc[i][j], 0, 0, 0);
    }
    __builtin_amdgcn_s_setprio(0);
    __builtin_amdgcn_sched_barrier(0);
    __builtin_amdgcn_s_barrier();
  }
#undef STAGE8

  if constexpr (LNA) {
#pragma unroll
    for (int i = 0; i < IM; ++i) {
      sA[i] += __shfl_xor(sA[i], 16); sA[i] += __shfl_xor(sA[i], 32);
      sQ[i] += __shfl_xor(sQ[i], 16); sQ[i] += __shfl_xor(sQ[i], 32);
    }
    __syncthreads();                 // everyone past the K-loop before overwrite
    if (kg == 0) {
#pragma unroll
      for (int i = 0; i < IM; ++i)
        statsL[wr * RPW + i * 16 + r15] = make_float2(sA[i], sQ[i]);
    }
    __syncthreads();
  }

#pragma unroll
  for (int i = 0; i < IM; ++i) {
#pragma unroll
    for (int j = 0; j < JN; ++j) {
      int col = bm + wc * CPW + j * 16 + r15;
      float bv = bias[col];
      float sc = 0.f, ba = 0.f;
      if (LNA) { sc = scol[col]; ba = badd[col]; }
#pragma unroll
      for (int r = 0; r < 4; ++r) {
        int row = bn + wr * RPW + i * 16 + kg * 4 + r;
        size_t idx = (size_t)row * M + col;
        if (EPI == 8 || EPI == 9) {
          float2 st = statsL[row - bn];
          float mean = st.x * (1.f / 512.f);
          float var = st.y * (1.f / 512.f) - mean * mean;
          float rs = rsqrtf(var + 1e-5f);
          float o = rs * acc[i][j][r] - rs * mean * sc + bv + ba;
          if (EPI == 9) o = fmaxf(o, 0.f);
          ((u16*)Cout)[idx] = f2bf(o);
        } else {
          float v = acc[i][j][r] + bv;
          if (EPI == 1) v = fmaxf(v, 0.f);
          if (EPI == 3) {
            ((u16*)Cout)[idx] = f2bf(((const float*)res)[idx] + v);
          } else if (EPI == 4) {
            ((u16*)Cout)[idx] = f2bf(bf2f(((const u16*)res)[idx]) + v);
          } else if (EPI == 5) {
            ((float*)Cout)[idx] = bf2f(((const u16*)res)[idx]) + v;
          } else {
            ((u16*)Cout)[idx] = f2bf(v);
          }
        }
      }
    }
  }
}

template <int EPI, int BM, int BN, int WRg, int MINW>
__global__ __launch_bounds__(512, MINW) void gemm8(const u16* __restrict__ A,
                                                   const u16* __restrict__ Bw,
                                                   const float* __restrict__ bias,
                                                   const void* __restrict__ res,
                                                   void* __restrict__ Cout,
                                                   int N, int M, int K,
                                                   const float* scol = nullptr,
                                                   const float* badd = nullptr) {
  __shared__ __align__(16) u16 lds[2 * (BM + BN) * 64];
  const int nwg = gridDim.x * gridDim.y;
  const int id = blockIdx.y * gridDim.x + blockIdx.x;
  const int swz = (id & 7) * (nwg >> 3) + (id >> 3);
  const int bn = (swz / gridDim.x) * BM;
  const int bm = (swz % gridDim.x) * BN;
  gemm8_body<EPI, BM, BN, WRg>(A, Bw, bias, res, Cout, M, K, bn, bm, lds, scol, badd);
}

// union: QKV_s (8192x1536x512, 128x128, 768 blocks) + KV_c (4096x1024x512, 64x128, 512 blocks)
__global__ __launch_bounds__(512, 4) void gemm_qkvkv(const u16* __restrict__ A0, const u16* __restrict__ W0,
                                                     const float* __restrict__ c0, u16* __restrict__ O0,
                                                     const u16* __restrict__ A1, const u16* __restrict__ W1,
                                                     const float* __restrict__ c1, u16* __restrict__ O1) {
  __shared__ __align__(16) u16 lds[2 * 256 * 64];
  const int id = blockIdx.x;
  if (id < 768) {
    const int swz = (id & 7) * 96 + (id >> 3);
    gemm8_body<0, 128, 128, 4>(A0, W0, c0, nullptr, O0, 1536, 512,
                               (swz / 12) * 128, (swz % 12) * 128, lds);
  } else {
    const int lid = id - 768;
    const int swz = (lid & 7) * 64 + (lid >> 3);
    gemm8_body<0, 64, 128, 2>(A1, W1, c1, nullptr, O1, 1024, 512,
                              (swz / 8) * 64, (swz % 8) * 128, lds);
  }
}

// ---------------- flash attention v8: 4 waves/block, 128 q-rows, 2 blocks/CU ----------------
__global__ __launch_bounds__(256, 2) void attn_kernel(const u16* __restrict__ qB,
                                                      const u16* __restrict__ kB,
                                                      const u16* __restrict__ vtB,
                                                      u16* __restrict__ oB,
                                                      int qStride, int kvStride, int Sk) {
  __shared__ __align__(16) u16 lK[4][64 * 64];
  __shared__ __align__(16) u16 lVt[4][64 * 64];
  const int tid = threadIdx.x, lane = tid & 63, w = tid >> 6;
  const int sid = blockIdx.x;
  const int h = sid & 7, b = (sid >> 3) & 7, qt = sid >> 6;
  const int r15 = lane & 15, kg = lane >> 4;
  const int srow = lane >> 3;
  const int sxcol = ((lane & 7) * 8) ^ (srow * 8);

  const int q0 = qt * 128 + w * 32 + r15;
  const u16* qrow0 = qB + (size_t)(q0 * 8 + b) * qStride + h * 64;
  const u16* qrow1 = qB + (size_t)((q0 + 16) * 8 + b) * qStride + h * 64;
  bfx8 qf0a = *(const bfx8*)(qrow0 + kg * 8);
  bfx8 qf0b = *(const bfx8*)(qrow0 + 32 + kg * 8);
  bfx8 qf1a = *(const bfx8*)(qrow1 + kg * 8);
  bfx8 qf1b = *(const bfx8*)(qrow1 + 32 + kg * 8);

  const int rlA = w * 16 + srow;
  const int rlB = rlA + 8;
  const int krA = (rlA & 32) | ((rlA & 12) << 1) | ((rlA & 16) >> 2) | (rlA & 3);
  const int krB = (rlB & 32) | ((rlB & 12) << 1) | ((rlB & 16) >> 2) | (rlB & 3);

  const u16* vbase = vtB + ((size_t)(b * 8 + h) * 64) * Sk;
  const u16* kpA = kB + ((size_t)krA * 8 + b) * kvStride + h * 64 + sxcol;
  const u16* kpB = kB + ((size_t)krB * 8 + b) * kvStride + h * 64 + sxcol;
  const size_t kAdv = (size_t)64 * 8 * kvStride;
  const u16* vpA = vbase + (size_t)rlA * Sk + sxcol;
  const u16* vpB = vbase + (size_t)rlB * Sk + sxcol;

#define STAGE(buf, tt) do {                                                           \
    __builtin_amdgcn_global_load_lds((AS1 u32*)(kpA + (size_t)(tt) * kAdv),           \
                                     (AS3 u32*)&lK[buf][(w * 16) * 64], 16, 0, 0);    \
    __builtin_amdgcn_global_load_lds((AS1 u32*)(kpB + (size_t)(tt) * kAdv),           \
                                     (AS3 u32*)&lK[buf][(w * 16 + 8) * 64], 16, 0, 0);\
    __builtin_amdgcn_global_load_lds((AS1 u32*)(vpA + (size_t)(tt) * 64),             \
                                     (AS3 u32*)&lVt[buf][(w * 16) * 64], 16, 0, 0);   \
    __builtin_amdgcn_global_load_lds((AS1 u32*)(vpB + (size_t)(tt) * 64),             \
                                     (AS3 u32*)&lVt[buf][(w * 16 + 8) * 64], 16, 0, 0);\
  } while (0)

  const int nt = Sk / 64;
  const int np = nt >> 1;
  STAGE(0, 0); STAGE(1, 1);

  f32x4 oacc0[4] = {}, oacc1[4] = {};
  float mrow0 = -1e30f, mrow1 = -1e30f, lsum0 = 0.f, lsum1 = 0.f;
  const float C2 = 0.125f * 1.44269504088896340736f;
  const int xr = (r15 & 7) << 4;

  for (int i = 0; i < np; ++i) {
    __builtin_amdgcn_sched_barrier(0);
    __builtin_amdgcn_s_barrier();
    __builtin_amdgcn_sched_barrier(0);
    if (i + 1 < np) {
      const int sb = ((i + 1) & 1) * 2;
      STAGE(sb, 2 * (i + 1)); STAGE(sb + 1, 2 * (i + 1) + 1);
      asm volatile("s_waitcnt vmcnt(8)" ::: "memory");
    } else {
      asm volatile("s_waitcnt vmcnt(0)" ::: "memory");
    }
    __builtin_amdgcn_sched_barrier(0);

#pragma unroll
    for (int tb = 0; tb < 2; ++tb) {
      const int buf = (i & 1) * 2 + tb;
      const char* Kc = (const char*)lK[buf];
      const char* Vc = (const char*)lVt[buf];

      f32x4 s0[4] = {}, s1[4] = {};
      __builtin_amdgcn_s_setprio(1);
#pragma unroll
      for (int j = 0; j < 4; ++j) {
        const char* kp = Kc + (j * 16 + r15) * 128;
        bfx8 kf0 = *(const bfx8*)(kp + ((kg * 16) ^ xr));
        bfx8 kf1 = *(const bfx8*)(kp + ((64 + kg * 16) ^ xr));
        s0[j] = __builtin_amdgcn_mfma_f32_16x16x32_bf16(kf0, qf0a, s0[j], 0, 0, 0);
        s0[j] = __builtin_amdgcn_mfma_f32_16x16x32_bf16(kf1, qf0b, s0[j], 0, 0, 0);
        s1[j] = __builtin_amdgcn_mfma_f32_16x16x32_bf16(kf0, qf1a, s1[j], 0, 0, 0);
        s1[j] = __builtin_amdgcn_mfma_f32_16x16x32_bf16(kf1, qf1b, s1[j], 0, 0, 0);
      }
      __builtin_amdgcn_s_setprio(0);

      float lm0 = fmaxf(fmaxf(fmaxf(s0[0][0], s0[0][1]), fmaxf(s0[0][2], s0[0][3])),
                 fmaxf(fmaxf(fmaxf(s0[1][0], s0[1][1]), fmaxf(s0[1][2], s0[1][3])),
                 fmaxf(fmaxf(fmaxf(s0[2][0], s0[2][1]), fmaxf(s0[2][2], s0[2][3])),
                       fmaxf(fmaxf(s0[3][0], s0[3][1]), fmaxf(s0[3][2], s0[3][3])))));
      if (!__all(lm0 <= mrow0 + 16.0f)) {
        float m0 = fmaxf(lm0, __shfl_xor(lm0, 16));
        m0 = fmaxf(m0, __shfl_xor(m0, 32));
        float mn = fmaxf(mrow0, m0);
        float corr = fexp2((mrow0 - mn) * C2);
        mrow0 = mn;
        lsum0 *= corr;
#pragma unroll
        for (int jd = 0; jd < 4; ++jd)
#pragma unroll
          for (int r = 0; r < 4; ++r) oacc0[jd][r] *= corr;
      }
      float lm1 = fmaxf(fmaxf(fmaxf(s1[0][0], s1[0][1]), fmaxf(s1[0][2], s1[0][3])),
                 fmaxf(fmaxf(fmaxf(s1[1][0], s1[1][1]), fmaxf(s1[1][2], s1[1][3])),
                 fmaxf(fmaxf(fmaxf(s1[2][0], s1[2][1]), fmaxf(s1[2][2], s1[2][3])),
                       fmaxf(fmaxf(s1[3][0], s1[3][1]), fmaxf(s1[3][2], s1[3][3])))));
      if (!__all(lm1 <= mrow1 + 16.0f)) {
        float m1 = fmaxf(lm1, __shfl_xor(lm1, 16));
        m1 = fmaxf(m1, __shfl_xor(m1, 32));
        float mn = fmaxf(mrow1, m1);
        float corr = fexp2((mrow1 - mn) * C2);
        mrow1 = mn;
        lsum1 *= corr;
#pragma unroll
        for (int jd = 0; jd < 4; ++jd)
#pragma unroll
          for (int r = 0; r < 4; ++r) oacc1[jd][r] *= corr;
      }

      float bc0 = -mrow0 * C2, bc1 = -mrow1 * C2;
      float p0[4][4], p1[4][4];
      float ps0 = 0.f, ps1 = 0.f;
#pragma unroll
      for (int j = 0; j < 4; ++j)
#pragma unroll
        for (int r = 0; r < 4; ++r) {
          p0[j][r] = fexp2(fmaf(s0[j][r], C2, bc0));
          p1[j][r] = fexp2(fmaf(s1[j][r], C2, bc1));
          ps0 += p0[j][r]; ps1 += p1[j][r];
        }
      lsum0 += ps0; lsum1 += ps1;

      __builtin_amdgcn_s_setprio(1);
#pragma unroll
      for (int s2 = 0; s2 < 2; ++s2) {
        union { u32 u[4]; bfx8 v; } pt0, pt1;
        pt0.u[0] = cvt_pk_bf16(p0[2 * s2][0],     p0[2 * s2][1]);
        pt0.u[1] = cvt_pk_bf16(p0[2 * s2][2],     p0[2 * s2][3]);
        pt0.u[2] = cvt_pk_bf16(p0[2 * s2 + 1][0], p0[2 * s2 + 1][1]);
        pt0.u[3] = cvt_pk_bf16(p0[2 * s2 + 1][2], p0[2 * s2 + 1][3]);
        pt1.u[0] = cvt_pk_bf16(p1[2 * s2][0],     p1[2 * s2][1]);
        pt1.u[1] = cvt_pk_bf16(p1[2 * s2][2],     p1[2 * s2][3]);
        pt1.u[2] = cvt_pk_bf16(p1[2 * s2 + 1][0], p1[2 * s2 + 1][1]);
        pt1.u[3] = cvt_pk_bf16(p1[2 * s2 + 1][2], p1[2 * s2 + 1][3]);
#pragma unroll
        for (int jd = 0; jd < 4; ++jd) {
          const char* vp = Vc + (jd * 16 + r15) * 128;
          bfx8 vf = *(const bfx8*)(vp + ((s2 * 64 + kg * 16) ^ xr));
          oacc0[jd] = __builtin_amdgcn_mfma_f32_16x16x32_bf16(vf, pt0.v, oacc0[jd], 0, 0, 0);
          oacc1[jd] = __builtin_amdgcn_mfma_f32_16x16x32_bf16(vf, pt1.v, oacc1[jd], 0, 0, 0);
        }
      }
      __builtin_amdgcn_s_setprio(0);
    }
  }
#undef STAGE

  lsum0 += __shfl_xor(lsum0, 16);
  lsum0 += __shfl_xor(lsum0, 32);
  lsum1 += __shfl_xor(lsum1, 16);
  lsum1 += __shfl_xor(lsum1, 32);
  float inv0 = 1.f / lsum0, inv1 = 1.f / lsum1;
  u16* orow0 = oB + (size_t)(q0 * 8 + b) * 512 + h * 64;
  u16* orow1 = oB + (size_t)((q0 + 16) * 8 + b) * 512 + h * 64;
#pragma unroll
  for (int jd = 0; jd < 4; ++jd) {
    *(u32*)(orow0 + jd * 16 + kg * 4)     = cvt_pk_bf16(oacc0[jd][0] * inv0, oacc0[jd][1] * inv0);
    *(u32*)(orow0 + jd * 16 + kg * 4 + 2) = cvt_pk_bf16(oacc0[jd][2] * inv0, oacc0[jd][3] * inv0);
    *(u32*)(orow1 + jd * 16 + kg * 4)     = cvt_pk_bf16(oacc1[jd][0] * inv1, oacc1[jd][1] * inv1);
    *(u32*)(orow1 + jd * 16 + kg * 4 + 2) = cvt_pk_bf16(oacc1[jd][2] * inv1, oacc1[jd][3] * inv1);
  }
}

extern "C" void kernel_launch(void* const* d_in, const int* in_sizes, int n_in,
                              void* d_out, int out_size, void* d_ws, size_t ws_size,
                              hipStream_t stream) {
  const float* rna    = (const float*)d_in[0];
  const float* prot   = (const float*)d_in[1];
  const float* Wqkv_s = (const float*)d_in[2];
  const float* bqkv_s = (const float*)d_in[3];
  const float* Wo_s   = (const float*)d_in[4];
  const float* bo_s   = (const float*)d_in[5];
  const float* Wqkv_c = (const float*)d_in[6];
  const float* bqkv_c = (const float*)d_in[7];
  const float* Wo_c   = (const float*)d_in[8];
  const float* bo_c   = (const float*)d_in[9];
  const float* W1     = (const float*)d_in[10];
  const float* b1     = (const float*)d_in[11];
  const float* W2     = (const float*)d_in[12];
  const float* b2     = (const float*)d_in[13];
  const float* g0  = (const float*)d_in[14];
  const float* be0 = (const float*)d_in[15];
  const float* g11 = (const float*)d_in[16];
  const float* be11= (const float*)d_in[17];
  const float* g12 = (const float*)d_in[18];
  const float* be12= (const float*)d_in[19];
  const float* g2  = (const float*)d_in[20];
  const float* be2 = (const float*)d_in[21];
  float* out = (float*)d_out;

  u16* wbf      = (u16*)d_ws;
  u16* w_qkv_s  = wbf;
  u16* w_o_s    = wbf + 786432;
  u16* w_qkv_c  = wbf + 1048576;   // Q slice gamma11-folded
  u16* w_o_c    = wbf + 1835008;
  u16* w_1      = wbf + 2097152;   // gamma2-folded
  u16* w_2      = wbf + 3145728;
  u16* hbuf     = wbf + 4194304;   // LN(rna) out / Vt_self
  u16* qkv      = hbuf + 4194304;
  u16* kvc      = qkv + 4194304;
  u16* attnO    = qkv + 12582912;
  u16* hp       = attnO + 4194304; // prot LN / Vt_cross
  u16* x1b      = hp + 2097152;
  u16* x1c      = x1b + 4194304;
  u16* ffnmid   = qkv;
  float* s_qc    = (float*)(x1c + 4194304);
  float* badd_qc = s_qc + 512;
  float* s_f1    = s_qc + 1024;
  float* badd_f1 = s_qc + 3072;

  // 1. weights cvt (gamma-folded) + LN(rna) + LN(protein) + LN-commute column reductions
  cvtln_kernel<<<7808, 256, 0, stream>>>(Wqkv_s, Wo_s, Wqkv_c, Wo_c, W1, W2,
                                         w_qkv_s, w_o_s, w_qkv_c, w_o_c, w_1, w_2,
                                         rna, g0, be0, hbuf, prot, g12, be12, hp,
                                         g11, be11, g2, be2,
                                         s_qc, badd_qc, s_f1, badd_f1);

  // 2. union GEMM: QKV_s + KV_c
  gemm_qkvkv<<<1280, 512, 0, stream>>>(hbuf, w_qkv_s, bqkv_s, qkv,
                                       hp, w_qkv_c + 512 * 512, bqkv_c + 512, kvc);

  // 3. both V transposes
  vt2_kernel<<<1536, 256, 0, stream>>>(qkv + 1024, hbuf, kvc + 512, hp);

  // 4-5. self attention + O_s (residual rna fp32 -> x1b bf16)
  attn_kernel<<<512, 256, 0, stream>>>(qkv, qkv + 512, hbuf, attnO, 1536, 1536, 1024);
  gemm8<3, 64, 128, 2, 6><<<dim3(4, 128), 512, 0, stream>>>(attnO, w_o_s, bo_s, rna, x1b, 8192, 512, 512);

  // 6-8. cross attention: QKV_c fused-LN on raw x1b (gamma-folded W, commuted epilogue)
  gemm8<8, 64, 128, 2, 6><<<dim3(4, 128), 512, 0, stream>>>(x1b, w_qkv_c, bqkv_c, nullptr, qkv,
                                                            8192, 512, 512, s_qc, badd_qc);
  attn_kernel<<<512, 256, 0, stream>>>(qkv, kvc, hp, attnO, 512, 1024, 512);
  gemm8<4, 64, 128, 2, 6><<<dim3(4, 128), 512, 0, stream>>>(attnO, w_o_c, bo_c, x1b, x1c, 8192, 512, 512);

  // 9-10. FFN: FFN1 fused-LN on raw x1c
  gemm8<9, 128, 128, 4, 4><<<dim3(16, 64), 512, 0, stream>>>(x1c, w_1, b1, nullptr, ffnmid,
                                                             8192, 2048, 512, s_f1, badd_f1);
  gemm8<5, 64, 128, 2, 6><<<dim3(4, 128), 512, 0, stream>>>(ffnmid, w_2, b2, x1c, out, 8192, 512, 2048);
}

// Round 20
// 173.318 us; speedup vs baseline: 1.0414x; 1.0414x over previous
//
#include <hip/hip_runtime.h>

typedef unsigned short u16;
typedef unsigned int u32;
typedef u16 u16x8 __attribute__((ext_vector_type(8)));
typedef u16 u16x4 __attribute__((ext_vector_type(4)));
typedef short bfx8 __attribute__((ext_vector_type(8)));
typedef float f32x4 __attribute__((ext_vector_type(4)));

#define AS1 __attribute__((address_space(1)))
#define AS3 __attribute__((address_space(3)))

__device__ __forceinline__ u16 f2bf(float f) {
  union { float f; u32 u; } c; c.f = f;
  u32 u = c.u;
  u += 0x7fffu + ((u >> 16) & 1u);
  return (u16)(u >> 16);
}

__device__ __forceinline__ float bf2f(u16 b) {
  union { u32 u; float f; } c; c.u = ((u32)b) << 16;
  return c.f;
}

__device__ __forceinline__ u32 cvt_pk_bf16(float lo, float hi) {
  u32 r;
  asm("v_cvt_pk_bf16_f32 %0, %1, %2" : "=v"(r) : "v"(lo), "v"(hi));
  return r;
}

__device__ __forceinline__ float fexp2(float x) {
  float r;
  asm("v_exp_f32 %0, %1" : "=v"(r) : "v"(x));
  return r;
}

// ---------------- LN row helpers (D=512) ----------------
__device__ __forceinline__ void ln_core(float f[8], const float* __restrict__ g,
                                        const float* __restrict__ be,
                                        u16* __restrict__ out, int gw, int lane) {
  float s = 0.f, q = 0.f;
#pragma unroll
  for (int e = 0; e < 8; ++e) { s += f[e]; q += f[e] * f[e]; }
#pragma unroll
  for (int m = 1; m < 64; m <<= 1) { s += __shfl_xor(s, m); q += __shfl_xor(q, m); }
  float mean = s * (1.f / 512.f);
  float var = q * (1.f / 512.f) - mean * mean;
  float rs = rsqrtf(var + 1e-5f);
  const float4* g4 = (const float4*)g;
  const float4* b4 = (const float4*)be;
  float4 ga = g4[2 * lane], gb = g4[2 * lane + 1];
  float4 ba = b4[2 * lane], bb = b4[2 * lane + 1];
  float gv[8] = {ga.x, ga.y, ga.z, ga.w, gb.x, gb.y, gb.z, gb.w};
  float bv[8] = {ba.x, ba.y, ba.z, ba.w, bb.x, bb.y, bb.z, bb.w};
  u16x8 o;
#pragma unroll
  for (int e = 0; e < 8; ++e) o[e] = f2bf((f[e] - mean) * rs * gv[e] + bv[e]);
  ((u16x8*)(out + (size_t)gw * 512))[lane] = o;
}

__device__ __forceinline__ void ln_row_f32(const float* __restrict__ x, const float* __restrict__ g,
                                           const float* __restrict__ be, u16* __restrict__ out,
                                           int gw, int lane) {
  const float4* row = (const float4*)(x + (size_t)gw * 512);
  float4 a = row[2 * lane], b = row[2 * lane + 1];
  float f[8] = {a.x, a.y, a.z, a.w, b.x, b.y, b.z, b.w};
  ln_core(f, g, be, out, gw, lane);
}

__device__ __forceinline__ void ln_row_bf16(const u16* __restrict__ x, const float* __restrict__ g,
                                            const float* __restrict__ be, u16* __restrict__ out,
                                            int gw, int lane) {
  u16x8 v = ((const u16x8*)(x + (size_t)gw * 512))[lane];
  float f[8];
#pragma unroll
  for (int e = 0; e < 8; ++e) f[e] = bf2f(v[e]);
  ln_core(f, g, be, out, gw, lane);
}

// ---------------- merged: 6 weight cvts + LN(rna) + LN(protein) ----------------
__global__ __launch_bounds__(256) void cvtln_kernel(const float* __restrict__ a0, const float* __restrict__ a1,
                                                    const float* __restrict__ a2, const float* __restrict__ a3,
                                                    const float* __restrict__ a4, const float* __restrict__ a5,
                                                    u16* __restrict__ b0, u16* __restrict__ b1,
                                                    u16* __restrict__ b2, u16* __restrict__ b3,
                                                    u16* __restrict__ b4, u16* __restrict__ b5,
                                                    const float* __restrict__ x, const float* __restrict__ g,
                                                    const float* __restrict__ be, u16* __restrict__ lnout,
                                                    const float* __restrict__ xp, const float* __restrict__ gp,
                                                    const float* __restrict__ bep, u16* __restrict__ lnoutp) {
  if (blockIdx.x < 4096) {
    int i = blockIdx.x * 256 + threadIdx.x;
    const float* s; u16* d; int off;
    if      (i < 196608) { s = a0; d = b0; off = i; }
    else if (i < 262144) { s = a1; d = b1; off = i - 196608; }
    else if (i < 458752) { s = a2; d = b2; off = i - 262144; }
    else if (i < 524288) { s = a3; d = b3; off = i - 458752; }
    else if (i < 786432) { s = a4; d = b4; off = i - 524288; }
    else                 { s = a5; d = b5; off = i - 786432; }
    float4 v = ((const float4*)s)[off];
    u16x4 o;
    o[0] = f2bf(v.x); o[1] = f2bf(v.y); o[2] = f2bf(v.z); o[3] = f2bf(v.w);
    ((u16x4*)d)[off] = o;
  } else if (blockIdx.x < 6144) {
    int gw = ((blockIdx.x - 4096) * 256 + threadIdx.x) >> 6;
    ln_row_f32(x, g, be, lnout, gw, threadIdx.x & 63);
  } else {
    int gw = ((blockIdx.x - 6144) * 256 + threadIdx.x) >> 6;
    ln_row_f32(xp, gp, bep, lnoutp, gw, threadIdx.x & 63);
  }
}

// ---------------- LN (bf16 in) ----------------
__global__ __launch_bounds__(256) void lnb_kernel(const u16* __restrict__ x,
                                                  const float* __restrict__ g,
                                                  const float* __restrict__ be,
                                                  u16* __restrict__ out, int ntok) {
  int gw = (blockIdx.x * 256 + threadIdx.x) >> 6;
  if (gw >= ntok) return;
  ln_row_bf16(x, g, be, out, gw, threadIdx.x & 63);
}

// ---------------- V transpose body ----------------
__device__ __forceinline__ void vt_body(const u16* __restrict__ vB, u16* __restrict__ vt,
                                        int stride, int S, int xblk, int b, int h) {
  __shared__ u16 lt[64 * 68];
  const int t = threadIdx.x;
  const int sr = t >> 3, dc = (t & 7) * 8;
#pragma unroll
  for (int p = 0; p < 2; ++p) {
    int s = xblk * 64 + sr + p * 32;
    u16x8 v = *(const u16x8*)(vB + (size_t)(s * 8 + b) * stride + h * 64 + dc);
    u16x4 lo, hi;
    lo[0]=v[0]; lo[1]=v[1]; lo[2]=v[2]; lo[3]=v[3];
    hi[0]=v[4]; hi[1]=v[5]; hi[2]=v[6]; hi[3]=v[7];
    *(u16x4*)&lt[(sr + p * 32) * 68 + dc] = lo;
    *(u16x4*)&lt[(sr + p * 32) * 68 + dc + 4] = hi;
  }
  __syncthreads();
#pragma unroll
  for (int p = 0; p < 2; ++p) {
    int d = sr + p * 32;
    u16x8 o;
#pragma unroll
    for (int e = 0; e < 8; ++e) o[e] = lt[(dc + e) * 68 + d];
    *(u16x8*)(vt + ((size_t)(b * 8 + h) * 64 + d) * S + xblk * 64 + dc) = o;
  }
}

__global__ __launch_bounds__(256) void vt2_kernel(const u16* __restrict__ v0, u16* __restrict__ t0,
                                                  const u16* __restrict__ v1, u16* __restrict__ t1) {
  int id = blockIdx.x;
  if (id < 1024) {
    vt_body(v0, t0, 1536, 1024, id & 15, (id >> 4) & 7, id >> 7);
  } else {
    int l = id - 1024;
    vt_body(v1, t1, 1024, 512, l & 7, (l >> 3) & 7, l >> 6);
  }
}

// ---------------- gemm8 body: BM x BN tile, 8 waves (WRg x 8/WRg), dbuf, counted-vmcnt ----------------
// EPI: 0 bf16 | 1 bf16+relu | 3 fp32res->bf16 | 4 bf16res->bf16 | 5 bf16res->fp32
template <int EPI, int BM, int BN, int WRg>
__device__ __forceinline__ void gemm8_body(const u16* __restrict__ A,
                                           const u16* __restrict__ Bw,
                                           const float* __restrict__ bias,
                                           const void* __restrict__ res,
                                           void* __restrict__ Cout,
                                           int M, int K, int bn, int bm,
                                           u16* __restrict__ lds) {
  constexpr int WCg = 8 / WRg;
  constexpr int RPW = BM / WRg;
  constexpr int IM = RPW / 16;
  constexpr int CPW = BN / WCg;
  constexpr int JN = CPW / 16;
  constexpr int LD = (BM + BN) / 64;
  u16* lA = lds;
  u16* lB = lds + 2 * BM * 64;
  const int tid = threadIdx.x;
  const int lane = tid & 63, w = tid >> 6;
  const int wr = w / WCg, wc = w % WCg;
  const int r15 = lane & 15, kg = lane >> 4;
  const int xr = (r15 & 7) << 4;

  f32x4 acc[IM][JN] = {};

  const int lrw = tid >> 3;
  const int lcl = ((tid & 7) * 8) ^ ((lrw & 7) * 8);
  const u16* gA = A + (size_t)(bn + lrw) * K + lcl;
  const u16* gB = Bw + (size_t)(bm + lrw) * K + lcl;
  const int ldsbase = (w * 8) * 64;

#define STAGE8(buf, t) do {                                                               \
    _Pragma("unroll")                                                                     \
    for (int i_ = 0; i_ < BM / 64; ++i_)                                                  \
      __builtin_amdgcn_global_load_lds((AS1 u32*)(gA + (size_t)(i_ * 64) * K + (t) * 64), \
                                       (AS3 u32*)&lA[(buf) * BM * 64 + i_ * 4096 + ldsbase], 16, 0, 0);\
    _Pragma("unroll")                                                                     \
    for (int i_ = 0; i_ < BN / 64; ++i_)                                                  \
      __builtin_amdgcn_global_load_lds((AS1 u32*)(gB + (size_t)(i_ * 64) * K + (t) * 64), \
                                       (AS3 u32*)&lB[(buf) * BN * 64 + i_ * 4096 + ldsbase], 16, 0, 0);\
  } while (0)

  const int nk = K >> 6;
  STAGE8(0, 0);
  for (int t = 0; t < nk; ++t) {
    const int cur = t & 1;
    if (t + 1 < nk) {
      STAGE8(cur ^ 1, t + 1);
      if constexpr (LD == 3)      asm volatile("s_waitcnt vmcnt(3)" ::: "memory");
      else if constexpr (LD == 4) asm volatile("s_waitcnt vmcnt(4)" ::: "memory");
      else                        asm volatile("s_waitcnt vmcnt(8)" ::: "memory");
    } else {
      asm volatile("s_waitcnt vmcnt(0)" ::: "memory");
    }
    __builtin_amdgcn_sched_barrier(0);
    __builtin_amdgcn_s_barrier();
    __builtin_amdgcn_sched_barrier(0);

    const char* Ac = (const char*)&lA[cur * BM * 64];
    const char* Bc = (const char*)&lB[cur * BN * 64];
    __builtin_amdgcn_s_setprio(1);
#pragma unroll
    for (int kk = 0; kk < 2; ++kk) {
      bfx8 a[IM], b[JN];
#pragma unroll
      for (int i = 0; i < IM; ++i)
        a[i] = *(const bfx8*)(Ac + (wr * RPW + i * 16 + r15) * 128 + ((kk * 64 + kg * 16) ^ xr));
#pragma unroll
      for (int j = 0; j < JN; ++j)
        b[j] = *(const bfx8*)(Bc + (wc * CPW + j * 16 + r15) * 128 + ((kk * 64 + kg * 16) ^ xr));
#pragma unroll
      for (int i = 0; i < IM; ++i)
#pragma unroll
        for (int j = 0; j < JN; ++j)
          acc[i][j] = __builtin_amdgcn_mfma_f32_16x16x32_bf16(a[i], b[j], acc[i][j], 0, 0, 0);
    }
    __builtin_amdgcn_s_setprio(0);
    __builtin_amdgcn_sched_barrier(0);
    __builtin_amdgcn_s_barrier();
  }
#undef STAGE8

#pragma unroll
  for (int i = 0; i < IM; ++i) {
#pragma unroll
    for (int j = 0; j < JN; ++j) {
      int col = bm + wc * CPW + j * 16 + r15;
      float bv = bias[col];
#pragma unroll
      for (int r = 0; r < 4; ++r) {
        int row = bn + wr * RPW + i * 16 + kg * 4 + r;
        size_t idx = (size_t)row * M + col;
        float v = acc[i][j][r] + bv;
        if (EPI == 1) v = fmaxf(v, 0.f);
        if (EPI == 3) {
          ((u16*)Cout)[idx] = f2bf(((const float*)res)[idx] + v);
        } else if (EPI == 4) {
          ((u16*)Cout)[idx] = f2bf(bf2f(((const u16*)res)[idx]) + v);
        } else if (EPI == 5) {
          ((float*)Cout)[idx] = bf2f(((const u16*)res)[idx]) + v;
        } else {
          ((u16*)Cout)[idx] = f2bf(v);
        }
      }
    }
  }
}

template <int EPI, int BM, int BN, int WRg, int MINW>
__global__ __launch_bounds__(512, MINW) void gemm8(const u16* __restrict__ A,
                                                   const u16* __restrict__ Bw,
                                                   const float* __restrict__ bias,
                                                   const void* __restrict__ res,
                                                   void* __restrict__ Cout,
                                                   int N, int M, int K) {
  __shared__ __align__(16) u16 lds[2 * (BM + BN) * 64];
  const int nwg = gridDim.x * gridDim.y;
  const int id = blockIdx.y * gridDim.x + blockIdx.x;
  const int swz = (id & 7) * (nwg >> 3) + (id >> 3);
  const int bn = (swz / gridDim.x) * BM;
  const int bm = (swz % gridDim.x) * BN;
  gemm8_body<EPI, BM, BN, WRg>(A, Bw, bias, res, Cout, M, K, bn, bm, lds);
}

// union: QKV_s (8192x1536x512, 128x128, 768 blocks) + KV_c (4096x1024x512, 64x128, 512 blocks)
__global__ __launch_bounds__(512, 4) void gemm_qkvkv(const u16* __restrict__ A0, const u16* __restrict__ W0,
                                                     const float* __restrict__ c0, u16* __restrict__ O0,
                                                     const u16* __restrict__ A1, const u16* __restrict__ W1,
                                                     const float* __restrict__ c1, u16* __restrict__ O1) {
  __shared__ __align__(16) u16 lds[2 * 256 * 64];
  const int id = blockIdx.x;
  if (id < 768) {
    const int swz = (id & 7) * 96 + (id >> 3);
    gemm8_body<0, 128, 128, 4>(A0, W0, c0, nullptr, O0, 1536, 512,
                               (swz / 12) * 128, (swz % 12) * 128, lds);
  } else {
    const int lid = id - 768;
    const int swz = (lid & 7) * 64 + (lid >> 3);
    gemm8_body<0, 64, 128, 2>(A1, W1, c1, nullptr, O1, 1024, 512,
                              (swz / 8) * 64, (swz % 8) * 128, lds);
  }
}

// ---------------- flash attention v7: 8 waves/block, 256 q-rows, 2 q-groups/wave ----------------
__global__ __launch_bounds__(512, 2) void attn_kernel(const u16* __restrict__ qB,
                                                      const u16* __restrict__ kB,
                                                      const u16* __restrict__ vtB,
                                                      u16* __restrict__ oB,
                                                      int qStride, int kvStride, int Sk) {
  __shared__ __align__(16) u16 lK[4][64 * 64];
  __shared__ __align__(16) u16 lVt[4][64 * 64];
  const int tid = threadIdx.x, lane = tid & 63, w = tid >> 6;
  const int sid = blockIdx.x;
  const int h = sid & 7, b = (sid >> 3) & 7, qt = sid >> 6;
  const int r15 = lane & 15, kg = lane >> 4;
  const int srow = lane >> 3;
  const int sxcol = ((lane & 7) * 8) ^ (srow * 8);

  const int q0 = qt * 256 + w * 32 + r15;
  const u16* qrow0 = qB + (size_t)(q0 * 8 + b) * qStride + h * 64;
  const u16* qrow1 = qB + (size_t)((q0 + 16) * 8 + b) * qStride + h * 64;
  bfx8 qf0a = *(const bfx8*)(qrow0 + kg * 8);
  bfx8 qf0b = *(const bfx8*)(qrow0 + 32 + kg * 8);
  bfx8 qf1a = *(const bfx8*)(qrow1 + kg * 8);
  bfx8 qf1b = *(const bfx8*)(qrow1 + 32 + kg * 8);

  const int rl = w * 8 + srow;
  const int krow = (rl & 32) | ((rl & 12) << 1) | ((rl & 16) >> 2) | (rl & 3);

  const u16* vbase = vtB + ((size_t)(b * 8 + h) * 64) * Sk;
  const u16* kp0 = kB + ((size_t)krow * 8 + b) * kvStride + h * 64 + sxcol;
  const size_t kAdv = (size_t)64 * 8 * kvStride;
  const u16* vp0 = vbase + (size_t)rl * Sk + sxcol;

#define STAGE(buf, tt) do {                                                           \
    __builtin_amdgcn_global_load_lds((AS1 u32*)(kp0 + (size_t)(tt) * kAdv),           \
                                     (AS3 u32*)&lK[buf][(w * 8) * 64], 16, 0, 0);     \
    __builtin_amdgcn_global_load_lds((AS1 u32*)(vp0 + (size_t)(tt) * 64),             \
                                     (AS3 u32*)&lVt[buf][(w * 8) * 64], 16, 0, 0);    \
  } while (0)

  const int nt = Sk / 64;
  const int np = nt >> 1;
  STAGE(0, 0); STAGE(1, 1);

  f32x4 oacc0[4] = {}, oacc1[4] = {};
  float mrow0 = -1e30f, mrow1 = -1e30f, lsum0 = 0.f, lsum1 = 0.f;
  const float C2 = 0.125f * 1.44269504088896340736f;
  const int xr = (r15 & 7) << 4;

  for (int i = 0; i < np; ++i) {
    __builtin_amdgcn_sched_barrier(0);
    __builtin_amdgcn_s_barrier();
    __builtin_amdgcn_sched_barrier(0);
    if (i + 1 < np) {
      const int sb = ((i + 1) & 1) * 2;
      STAGE(sb, 2 * (i + 1)); STAGE(sb + 1, 2 * (i + 1) + 1);
      asm volatile("s_waitcnt vmcnt(4)" ::: "memory");
    } else {
      asm volatile("s_waitcnt vmcnt(0)" ::: "memory");
    }
    __builtin_amdgcn_sched_barrier(0);

#pragma unroll
    for (int tb = 0; tb < 2; ++tb) {
      const int buf = (i & 1) * 2 + tb;
      const char* Kc = (const char*)lK[buf];
      const char* Vc = (const char*)lVt[buf];

      f32x4 s0[4] = {}, s1[4] = {};
      __builtin_amdgcn_s_setprio(1);
#pragma unroll
      for (int j = 0; j < 4; ++j) {
        const char* kp = Kc + (j * 16 + r15) * 128;
        bfx8 kf0 = *(const bfx8*)(kp + ((kg * 16) ^ xr));
        bfx8 kf1 = *(const bfx8*)(kp + ((64 + kg * 16) ^ xr));
        s0[j] = __builtin_amdgcn_mfma_f32_16x16x32_bf16(kf0, qf0a, s0[j], 0, 0, 0);
        s0[j] = __builtin_amdgcn_mfma_f32_16x16x32_bf16(kf1, qf0b, s0[j], 0, 0, 0);
        s1[j] = __builtin_amdgcn_mfma_f32_16x16x32_bf16(kf0, qf1a, s1[j], 0, 0, 0);
        s1[j] = __builtin_amdgcn_mfma_f32_16x16x32_bf16(kf1, qf1b, s1[j], 0, 0, 0);
      }
      __builtin_amdgcn_s_setprio(0);

      float lm0 = fmaxf(fmaxf(fmaxf(s0[0][0], s0[0][1]), fmaxf(s0[0][2], s0[0][3])),
                 fmaxf(fmaxf(fmaxf(s0[1][0], s0[1][1]), fmaxf(s0[1][2], s0[1][3])),
                 fmaxf(fmaxf(fmaxf(s0[2][0], s0[2][1]), fmaxf(s0[2][2], s0[2][3])),
                       fmaxf(fmaxf(s0[3][0], s0[3][1]), fmaxf(s0[3][2], s0[3][3])))));
      if (!__all(lm0 <= mrow0 + 16.0f)) {
        float m0 = fmaxf(lm0, __shfl_xor(lm0, 16));
        m0 = fmaxf(m0, __shfl_xor(m0, 32));
        float mn = fmaxf(mrow0, m0);
        float corr = fexp2((mrow0 - mn) * C2);
        mrow0 = mn;
        lsum0 *= corr;
#pragma unroll
        for (int jd = 0; jd < 4; ++jd)
#pragma unroll
          for (int r = 0; r < 4; ++r) oacc0[jd][r] *= corr;
      }
      float lm1 = fmaxf(fmaxf(fmaxf(s1[0][0], s1[0][1]), fmaxf(s1[0][2], s1[0][3])),
                 fmaxf(fmaxf(fmaxf(s1[1][0], s1[1][1]), fmaxf(s1[1][2], s1[1][3])),
                 fmaxf(fmaxf(fmaxf(s1[2][0], s1[2][1]), fmaxf(s1[2][2], s1[2][3])),
                       fmaxf(fmaxf(s1[3][0], s1[3][1]), fmaxf(s1[3][2], s1[3][3])))));
      if (!__all(lm1 <= mrow1 + 16.0f)) {
        float m1 = fmaxf(lm1, __shfl_xor(lm1, 16));
        m1 = fmaxf(m1, __shfl_xor(m1, 32));
        float mn = fmaxf(mrow1, m1);
        float corr = fexp2((mrow1 - mn) * C2);
        mrow1 = mn;
        lsum1 *= corr;
#pragma unroll
        for (int jd = 0; jd < 4; ++jd)
#pragma unroll
          for (int r = 0; r < 4; ++r) oacc1[jd][r] *= corr;
      }

      float bc0 = -mrow0 * C2, bc1 = -mrow1 * C2;
      float p0[4][4], p1[4][4];
      float ps0 = 0.f, ps1 = 0.f;
#pragma unroll
      for (int j = 0; j < 4; ++j)
#pragma unroll
        for (int r = 0; r < 4; ++r) {
          p0[j][r] = fexp2(fmaf(s0[j][r], C2, bc0));
          p1[j][r] = fexp2(fmaf(s1[j][r], C2, bc1));
          ps0 += p0[j][r]; ps1 += p1[j][r];
        }
      lsum0 += ps0; lsum1 += ps1;

      __builtin_amdgcn_s_setprio(1);
#pragma unroll
      for (int s2 = 0; s2 < 2; ++s2) {
        union { u32 u[4]; bfx8 v; } pt0, pt1;
        pt0.u[0] = cvt_pk_bf16(p0[2 * s2][0],     p0[2 * s2][1]);
        pt0.u[1] = cvt_pk_bf16(p0[2 * s2][2],     p0[2 * s2][3]);
        pt0.u[2] = cvt_pk_bf16(p0[2 * s2 + 1][0], p0[2 * s2 + 1][1]);
        pt0.u[3] = cvt_pk_bf16(p0[2 * s2 + 1][2], p0[2 * s2 + 1][3]);
        pt1.u[0] = cvt_pk_bf16(p1[2 * s2][0],     p1[2 * s2][1]);
        pt1.u[1] = cvt_pk_bf16(p1[2 * s2][2],     p1[2 * s2][3]);
        pt1.u[2] = cvt_pk_bf16(p1[2 * s2 + 1][0], p1[2 * s2 + 1][1]);
        pt1.u[3] = cvt_pk_bf16(p1[2 * s2 + 1][2], p1[2 * s2 + 1][3]);
#pragma unroll
        for (int jd = 0; jd < 4; ++jd) {
          const char* vp = Vc + (jd * 16 + r15) * 128;
          bfx8 vf = *(const bfx8*)(vp + ((s2 * 64 + kg * 16) ^ xr));
          oacc0[jd] = __builtin_amdgcn_mfma_f32_16x16x32_bf16(vf, pt0.v, oacc0[jd], 0, 0, 0);
          oacc1[jd] = __builtin_amdgcn_mfma_f32_16x16x32_bf16(vf, pt1.v, oacc1[jd], 0, 0, 0);
        }
      }
      __builtin_amdgcn_s_setprio(0);
    }
  }
#undef STAGE

  lsum0 += __shfl_xor(lsum0, 16);
  lsum0 += __shfl_xor(lsum0, 32);
  lsum1 += __shfl_xor(lsum1, 16);
  lsum1 += __shfl_xor(lsum1, 32);
  float inv0 = 1.f / lsum0, inv1 = 1.f / lsum1;
  u16* orow0 = oB + (size_t)(q0 * 8 + b) * 512 + h * 64;
  u16* orow1 = oB + (size_t)((q0 + 16) * 8 + b) * 512 + h * 64;
#pragma unroll
  for (int jd = 0; jd < 4; ++jd) {
    *(u32*)(orow0 + jd * 16 + kg * 4)     = cvt_pk_bf16(oacc0[jd][0] * inv0, oacc0[jd][1] * inv0);
    *(u32*)(orow0 + jd * 16 + kg * 4 + 2) = cvt_pk_bf16(oacc0[jd][2] * inv0, oacc0[jd][3] * inv0);
    *(u32*)(orow1 + jd * 16 + kg * 4)     = cvt_pk_bf16(oacc1[jd][0] * inv1, oacc1[jd][1] * inv1);
    *(u32*)(orow1 + jd * 16 + kg * 4 + 2) = cvt_pk_bf16(oacc1[jd][2] * inv1, oacc1[jd][3] * inv1);
  }
}

extern "C" void kernel_launch(void* const* d_in, const int* in_sizes, int n_in,
                              void* d_out, int out_size, void* d_ws, size_t ws_size,
                              hipStream_t stream) {
  const float* rna    = (const float*)d_in[0];
  const float* prot   = (const float*)d_in[1];
  const float* Wqkv_s = (const float*)d_in[2];
  const float* bqkv_s = (const float*)d_in[3];
  const float* Wo_s   = (const float*)d_in[4];
  const float* bo_s   = (const float*)d_in[5];
  const float* Wqkv_c = (const float*)d_in[6];
  const float* bqkv_c = (const float*)d_in[7];
  const float* Wo_c   = (const float*)d_in[8];
  const float* bo_c   = (const float*)d_in[9];
  const float* W1     = (const float*)d_in[10];
  const float* b1     = (const float*)d_in[11];
  const float* W2     = (const float*)d_in[12];
  const float* b2     = (const float*)d_in[13];
  const float* g0  = (const float*)d_in[14];
  const float* be0 = (const float*)d_in[15];
  const float* g11 = (const float*)d_in[16];
  const float* be11= (const float*)d_in[17];
  const float* g12 = (const float*)d_in[18];
  const float* be12= (const float*)d_in[19];
  const float* g2  = (const float*)d_in[20];
  const float* be2 = (const float*)d_in[21];
  float* out = (float*)d_out;

  u16* wbf      = (u16*)d_ws;
  u16* w_qkv_s  = wbf;
  u16* w_o_s    = wbf + 786432;
  u16* w_qkv_c  = wbf + 1048576;
  u16* w_o_c    = wbf + 1835008;
  u16* w_1      = wbf + 2097152;
  u16* w_2      = wbf + 3145728;
  u16* hbuf     = wbf + 4194304;            // 8192x512 bf16 (LN out / Vt_self)
  u16* qkv      = hbuf + 4194304;           // up to 8192x1536
  u16* kvc      = qkv + 4194304;            // cross K|V
  u16* attnO    = qkv + 12582912;           // 8192x512
  u16* hp       = attnO + 4194304;          // 4096x512 (prot LN / Vt_cross)
  u16* x1b      = hp + 2097152;             // x1 after self (bf16)
  u16* x1c      = x1b + 4194304;            // x1 after cross (bf16)
  u16* ffnmid   = qkv;                      // 8192x2048 (reuses qkv+attnO)

  // 1. weights cvt + LN(rna) + LN(protein)
  cvtln_kernel<<<7168, 256, 0, stream>>>(Wqkv_s, Wo_s, Wqkv_c, Wo_c, W1, W2,
                                         w_qkv_s, w_o_s, w_qkv_c, w_o_c, w_1, w_2,
                                         rna, g0, be0, hbuf, prot, g12, be12, hp);

  // 2. union GEMM: QKV_s + KV_c (both inputs ready)
  gemm_qkvkv<<<1280, 512, 0, stream>>>(hbuf, w_qkv_s, bqkv_s, qkv,
                                       hp, w_qkv_c + 512 * 512, bqkv_c + 512, kvc);

  // 3. both V transposes (Vt_self -> hbuf, Vt_cross -> hp)
  vt2_kernel<<<1536, 256, 0, stream>>>(qkv + 1024, hbuf, kvc + 512, hp);

  // 4-5. self attention + O_s (residual from fp32 rna -> bf16 x1b)
  attn_kernel<<<256, 512, 0, stream>>>(qkv, qkv + 512, hbuf, attnO, 1536, 1536, 1024);
  gemm8<3, 64, 128, 2, 6><<<dim3(4, 128), 512, 0, stream>>>(attnO, w_o_s, bo_s, rna, x1b, 8192, 512, 512);

  // 6-9. cross attention
  lnb_kernel<<<2048, 256, 0, stream>>>(x1b, g11, be11, hbuf, 8192);
  gemm8<0, 64, 128, 2, 6><<<dim3(4, 128), 512, 0, stream>>>(hbuf, w_qkv_c, bqkv_c, nullptr, qkv, 8192, 512, 512);
  attn_kernel<<<256, 512, 0, stream>>>(qkv, kvc, hp, attnO, 512, 1024, 512);
  gemm8<4, 64, 128, 2, 6><<<dim3(4, 128), 512, 0, stream>>>(attnO, w_o_c, bo_c, x1b, x1c, 8192, 512, 512);

  // 10-12. FFN
  lnb_kernel<<<2048, 256, 0, stream>>>(x1c, g2, be2, hbuf, 8192);
  gemm8<1, 128, 128, 4, 4><<<dim3(16, 64), 512, 0, stream>>>(hbuf, w_1, b1, nullptr, ffnmid, 8192, 2048, 512);
  gemm8<5, 64, 128, 2, 6><<<dim3(4, 128), 512, 0, stream>>>(ffnmid, w_2, b2, x1c, out, 8192, 512, 2048);
}